// Round 6
// baseline (184.455 us; speedup 1.0000x reference)
//
#include <hip/hip_runtime.h>

typedef __attribute__((ext_vector_type(8))) short short8;     // 8 bf16 = 4 VGPRs
typedef __attribute__((ext_vector_type(4))) float f32x4;
typedef __attribute__((ext_vector_type(4))) unsigned short u16x4;

#define NVEC 65536
#define DDIM 64
#define KCODES 1024
#define NELEM 4194304   // NVEC * DDIM
#define VPB 128         // vectors per block; grid 512 = 2 blocks/CU
#define MT 8            // m-tiles per wave (all of the block's 128 vectors)
#define CW 256          // codes per wave (quarter of codebook)
#define NT (CW / 16)    // 16 N-tiles per wave

// fp32 -> bf16 round-to-nearest-even (no NaN/inf in this problem)
static __device__ inline unsigned short f2bf(float f) {
  unsigned u = __builtin_bit_cast(unsigned, f);
  return (unsigned short)((u + 0x7FFFu + ((u >> 16) & 1u)) >> 16);
}
static __device__ inline float bf2f(unsigned short b) {
  return __builtin_bit_cast(float, (unsigned)b << 16);
}

// ---- kernel 1: cb -> bf16, en1[k] = 1 + ||e_bf||^2, zero loss cell ---------
__global__ __launch_bounds__(256) void vq_prep(const float* __restrict__ cb,
                                               unsigned short* __restrict__ cb_bf,
                                               float* __restrict__ en1,
                                               float* __restrict__ out) {
  int t = blockIdx.x * 256 + threadIdx.x;
  float4 v = ((const float4*)cb)[t];
  unsigned short b0 = f2bf(v.x), b1 = f2bf(v.y), b2 = f2bf(v.z), b3 = f2bf(v.w);
  u16x4 pk = {b0, b1, b2, b3};
  *(u16x4*)(cb_bf + (size_t)t * 4) = pk;
  float e0 = bf2f(b0), e1 = bf2f(b1), e2 = bf2f(b2), e3 = bf2f(b3);
  float s = (e0 * e0 + e1 * e1) + (e2 * e2 + e3 * e3);
  s += __shfl_xor(s, 1, 64);
  s += __shfl_xor(s, 2, 64);
  s += __shfl_xor(s, 4, 64);
  s += __shfl_xor(s, 8, 64);
  if ((t & 15) == 0) en1[t >> 4] = 1.0f + s;  // +1 keeps scores in [0.8,1.2]>0
  if (t == 0) out[NELEM] = 0.f;               // loss accumulator
}

// ---- kernel 2: MFMA argmin + gather + output + loss ------------------------
// Block = 4 waves, 128 vectors. EVERY wave holds all 8 m-tiles (A-frags in
// 64 VGPRs, converted once per block via LDS frag lines) and scans a 256-code
// quarter. Per nt: 2 B-loads (global->reg, L2-resident cb_bf) amortized over
// 8 m-tiles (~270 cyc compute) with EXPLICIT 1-deep register prefetch -> L2
// latency (~230 cyc) hidden by ILP alone; no K-loop barriers. Argmin as
// packed u32 key (p>0 -> bitcast monotone) | 10-bit idx; v_min_u32 update;
// cross-wave combine via LDS atomicMin.
__global__ __launch_bounds__(256, 2) void vq_main(
    const float* __restrict__ x, const float* __restrict__ cb,
    const unsigned short* __restrict__ cb_bf, const float* __restrict__ en1,
    float* __restrict__ out) {
  __shared__ alignas(16) unsigned short xs[MT * 2 * 64 * 8];  // 16 KB frag lines
  __shared__ float en_s[KCODES];  // 4 KB: 1+||e||^2 per code
  __shared__ unsigned skey[VPB];
  __shared__ float xn[VPB];

  const int tid = threadIdx.x;
  const int wid = tid >> 6;
  const int L = tid & 63;
  const int c16 = L & 15;
  const int q = L >> 4;
  const int vblk = blockIdx.x * VPB;
  const int cbase = wid * CW;

  ((float4*)en_s)[tid] = ((const float4*)en1)[tid];
  if (tid < VPB) skey[tid] = 0xFFFFFFFFu;

  // ---- preamble: this wave converts 2 m-tiles to bf16 frag lines + ||x||^2
#pragma unroll
  for (int half_i = 0; half_i < 2; ++half_i) {
    const int mt = wid * 2 + half_i;
    const float* xv = x + (size_t)(vblk + mt * 16 + c16) * DDIM + q * 8;
    float4 u0 = *(const float4*)(xv);
    float4 u1 = *(const float4*)(xv + 4);
    float4 u2 = *(const float4*)(xv + 32);
    float4 u3 = *(const float4*)(xv + 36);
    unsigned short h0 = f2bf(u0.x), h1 = f2bf(u0.y), h2 = f2bf(u0.z), h3 = f2bf(u0.w);
    unsigned short h4 = f2bf(u1.x), h5 = f2bf(u1.y), h6 = f2bf(u1.z), h7 = f2bf(u1.w);
    unsigned short g0 = f2bf(u2.x), g1 = f2bf(u2.y), g2 = f2bf(u2.z), g3 = f2bf(u2.w);
    unsigned short g4 = f2bf(u3.x), g5 = f2bf(u3.y), g6 = f2bf(u3.z), g7 = f2bf(u3.w);
    u16x4 p0 = {h0, h1, h2, h3}, p1 = {h4, h5, h6, h7};
    u16x4 p2 = {g0, g1, g2, g3}, p3 = {g4, g5, g6, g7};
    unsigned short* l0 = xs + ((size_t)(mt * 2 + 0) * 64 + L) * 8;
    unsigned short* l1 = xs + ((size_t)(mt * 2 + 1) * 64 + L) * 8;
    *(u16x4*)(l0) = p0;
    *(u16x4*)(l0 + 4) = p1;
    *(u16x4*)(l1) = p2;
    *(u16x4*)(l1 + 4) = p3;
    float s0 = bf2f(h0), s1 = bf2f(h1), s2 = bf2f(h2), s3 = bf2f(h3);
    float s4 = bf2f(h4), s5 = bf2f(h5), s6 = bf2f(h6), s7 = bf2f(h7);
    float w0 = bf2f(g0), w1 = bf2f(g1), w2 = bf2f(g2), w3 = bf2f(g3);
    float w4 = bf2f(g4), w5 = bf2f(g5), w6 = bf2f(g6), w7 = bf2f(g7);
    float sx = ((s0 * s0 + s1 * s1) + (s2 * s2 + s3 * s3)) +
               ((s4 * s4 + s5 * s5) + (s6 * s6 + s7 * s7)) +
               ((w0 * w0 + w1 * w1) + (w2 * w2 + w3 * w3)) +
               ((w4 * w4 + w5 * w5) + (w6 * w6 + w7 * w7));
    sx += __shfl_xor(sx, 16, 64);  // reduce over q (d-chunks)
    sx += __shfl_xor(sx, 32, 64);
    if (L < 16) xn[mt * 16 + L] = sx;
  }
  __syncthreads();  // xs/xn/en_s/skey ready

  // all 8 m-tiles' A-frags into registers (conflict-free ds_read_b128)
  short8 a[MT][2];
#pragma unroll
  for (int m = 0; m < MT; ++m) {
    a[m][0] = *(const short8*)(xs + ((m * 2 + 0) * 64 + L) * 8);
    a[m][1] = *(const short8*)(xs + ((m * 2 + 1) * 64 + L) * 8);
  }

  unsigned bestk[MT][4];
#pragma unroll
  for (int m = 0; m < MT; ++m)
#pragma unroll
    for (int r = 0; r < 4; ++r) bestk[m][r] = 0xFFFFFFFFu;

  // ---- K-loop: explicit 1-deep register prefetch of B-frags + env ----------
  const unsigned short* bp = cb_bf + (size_t)(cbase + c16) * DDIM + q * 8;
  short8 nb0 = *(const short8*)(bp);
  short8 nb1 = *(const short8*)(bp + 32);
  float nenv = en_s[cbase + c16];
#pragma unroll
  for (int nt = 0; nt < NT; ++nt) {
    short8 b0 = nb0, b1 = nb1;
    float env = nenv;
    if (nt < NT - 1) {
      nb0 = *(const short8*)(bp + (nt + 1) * 16 * DDIM);
      nb1 = *(const short8*)(bp + (nt + 1) * 16 * DDIM + 32);
      nenv = en_s[cbase + (nt + 1) * 16 + c16];
    }
    unsigned kidx = (unsigned)(cbase + nt * 16 + c16);
#pragma unroll
    for (int m = 0; m < MT; ++m) {
      f32x4 z = {0.f, 0.f, 0.f, 0.f};
      f32x4 acc = __builtin_amdgcn_mfma_f32_16x16x32_bf16(a[m][0], b0, z, 0, 0, 0);
      acc = __builtin_amdgcn_mfma_f32_16x16x32_bf16(a[m][1], b1, acc, 0, 0, 0);
#pragma unroll
      for (int r = 0; r < 4; ++r) {
        // p = (1+||e||^2) - 2 x.e  in [0.8,1.2] -> bitcast monotone
        float p = fmaf(-2.f, acc[r], env);
        unsigned key = (__builtin_bit_cast(unsigned, p) & 0xFFFFFC00u) | kidx;
        bestk[m][r] = key < bestk[m][r] ? key : bestk[m][r];
      }
    }
  }

  // fold 16 columns (lanes differing in c16), then cross-wave combine
#pragma unroll
  for (int m = 0; m < MT; ++m)
#pragma unroll
    for (int r = 0; r < 4; ++r) {
      unsigned k = bestk[m][r];
      k = min(k, (unsigned)__shfl_xor((int)k, 1, 64));
      k = min(k, (unsigned)__shfl_xor((int)k, 2, 64));
      k = min(k, (unsigned)__shfl_xor((int)k, 4, 64));
      k = min(k, (unsigned)__shfl_xor((int)k, 8, 64));
      if (c16 == 0) atomicMin(&skey[m * 16 + q * 4 + r], k);
    }
  __syncthreads();

  // gather fp32 codebook row -> output (x + (e-x) == e exactly in fp32 here)
#pragma unroll
  for (int i = 0; i < 8; ++i) {
    int f = i * 256 + tid;  // float4 id in block tile [0,2048)
    int v = f >> 4, d4 = f & 15;
    int id = (int)(skey[v] & 1023u);
    ((float4*)out)[(size_t)vblk * 16 + f] = ((const float4*)cb)[(size_t)id * 16 + d4];
  }

  // loss: dist^2 = (p_trunc - 1) + ||x_bf||^2 ; two atomics per block
  if (wid < 2) {
    int vslot = wid * 64 + L;
    unsigned k = skey[vslot];
    float pt = __builtin_bit_cast(float, k & 0xFFFFFC00u);
    float pl = (pt - 1.0f) + xn[vslot];
#pragma unroll
    for (int off = 32; off >= 1; off >>= 1) pl += __shfl_down(pl, off, 64);
    if (L == 0) atomicAdd(out + NELEM, pl * (1.25f / (float)NELEM));
  }
}

extern "C" void kernel_launch(void* const* d_in, const int* in_sizes, int n_in,
                              void* d_out, int out_size, void* d_ws,
                              size_t ws_size, hipStream_t stream) {
  const float* x = (const float*)d_in[0];   // [65536, 64]
  const float* cb = (const float*)d_in[1];  // [1024, 64]
  float* out = (float*)d_out;               // [NELEM] quantized + [1] loss
  char* ws = (char*)d_ws;
  unsigned short* cb_bf = (unsigned short*)ws;  // 128 KB
  float* en1 = (float*)(ws + 131072);           // 4 KB

  vq_prep<<<64, 256, 0, stream>>>(cb, cb_bf, en1, out);
  vq_main<<<NVEC / VPB, 256, 0, stream>>>(x, cb, cb_bf, en1, out);
}

// Round 7
// 167.388 us; speedup vs baseline: 1.1020x; 1.1020x over previous
//
#include <hip/hip_runtime.h>

typedef __attribute__((ext_vector_type(8))) short short8;     // 8 bf16 = 4 VGPRs
typedef __attribute__((ext_vector_type(4))) float f32x4;
typedef __attribute__((ext_vector_type(4))) unsigned short u16x4;

#define NVEC 65536
#define DDIM 64
#define KCODES 1024
#define NELEM 4194304   // NVEC * DDIM
#define VPB 64          // vectors per block; grid 1024 = 4 blocks/CU
#define MT 4            // m-tiles per wave (all 64 block vectors)
#define CW 256          // codes per wave (quarter of codebook)
#define NT (CW / 16)    // 16 N-tiles per wave

// fp32 -> bf16 round-to-nearest-even (no NaN/inf in this problem)
static __device__ inline unsigned short f2bf(float f) {
  unsigned u = __builtin_bit_cast(unsigned, f);
  return (unsigned short)((u + 0x7FFFu + ((u >> 16) & 1u)) >> 16);
}
static __device__ inline float bf2f(unsigned short b) {
  return __builtin_bit_cast(float, (unsigned)b << 16);
}

// ---- kernel 1: cb -> bf16, en1[k] = 1 + ||e_bf||^2 -------------------------
__global__ __launch_bounds__(256) void vq_prep(const float* __restrict__ cb,
                                               unsigned short* __restrict__ cb_bf,
                                               float* __restrict__ en1) {
  int t = blockIdx.x * 256 + threadIdx.x;
  float4 v = ((const float4*)cb)[t];
  unsigned short b0 = f2bf(v.x), b1 = f2bf(v.y), b2 = f2bf(v.z), b3 = f2bf(v.w);
  u16x4 pk = {b0, b1, b2, b3};
  *(u16x4*)(cb_bf + (size_t)t * 4) = pk;
  float e0 = bf2f(b0), e1 = bf2f(b1), e2 = bf2f(b2), e3 = bf2f(b3);
  float s = (e0 * e0 + e1 * e1) + (e2 * e2 + e3 * e3);
  s += __shfl_xor(s, 1, 64);
  s += __shfl_xor(s, 2, 64);
  s += __shfl_xor(s, 4, 64);
  s += __shfl_xor(s, 8, 64);
  if ((t & 15) == 0) en1[t >> 4] = 1.0f + s;  // +1 keeps scores in [0.8,1.2]>0
}

// ---- kernel 2: MFMA argmin + gather + output + loss partial ----------------
// Block = 4 waves, 64 vectors. Each wave: all 4 m-tiles (A-frags 32 VGPR,
// converted once via LDS frag lines) x a 256-code quarter; B-frags direct
// global->reg (cb_bf L2-resident) with explicit 1-deep prefetch; no K-loop
// barriers. ~110 VGPR: fits launch_bounds(256,4) cap=128 (NO spill; R6's
// MT=8 spilled at this cap -> 160 MB scratch traffic). Loss via per-block
// partial STORE (no device-scope same-address atomic storm). Argmin as
// packed u32 key (score>0 -> bitcast monotone) | 10-bit idx; v_min_u32.
__global__ __launch_bounds__(256, 4) void vq_main(
    const float* __restrict__ x, const float* __restrict__ cb,
    const unsigned short* __restrict__ cb_bf, const float* __restrict__ en1,
    float* __restrict__ out, float* __restrict__ partial) {
  __shared__ alignas(16) unsigned short xs[MT * 2 * 64 * 8];  // 8 KB frag lines
  __shared__ float en_s[KCODES];  // 4 KB: 1+||e||^2 per code
  __shared__ unsigned skey[VPB];
  __shared__ float xn[VPB];

  const int tid = threadIdx.x;
  const int wid = tid >> 6;
  const int L = tid & 63;
  const int c16 = L & 15;
  const int q = L >> 4;
  const int vblk = blockIdx.x * VPB;
  const int cbase = wid * CW;

  ((float4*)en_s)[tid] = ((const float4*)en1)[tid];
  if (tid < VPB) skey[tid] = 0xFFFFFFFFu;

  // ---- preamble: wave wid converts m-tile wid to bf16 frag lines + ||x||^2
  {
    const int mt = wid;
    const float* xv = x + (size_t)(vblk + mt * 16 + c16) * DDIM + q * 8;
    float4 u0 = *(const float4*)(xv);
    float4 u1 = *(const float4*)(xv + 4);
    float4 u2 = *(const float4*)(xv + 32);
    float4 u3 = *(const float4*)(xv + 36);
    unsigned short h0 = f2bf(u0.x), h1 = f2bf(u0.y), h2 = f2bf(u0.z), h3 = f2bf(u0.w);
    unsigned short h4 = f2bf(u1.x), h5 = f2bf(u1.y), h6 = f2bf(u1.z), h7 = f2bf(u1.w);
    unsigned short g0 = f2bf(u2.x), g1 = f2bf(u2.y), g2 = f2bf(u2.z), g3 = f2bf(u2.w);
    unsigned short g4 = f2bf(u3.x), g5 = f2bf(u3.y), g6 = f2bf(u3.z), g7 = f2bf(u3.w);
    u16x4 p0 = {h0, h1, h2, h3}, p1 = {h4, h5, h6, h7};
    u16x4 p2 = {g0, g1, g2, g3}, p3 = {g4, g5, g6, g7};
    unsigned short* l0 = xs + ((size_t)(mt * 2 + 0) * 64 + L) * 8;
    unsigned short* l1 = xs + ((size_t)(mt * 2 + 1) * 64 + L) * 8;
    *(u16x4*)(l0) = p0;
    *(u16x4*)(l0 + 4) = p1;
    *(u16x4*)(l1) = p2;
    *(u16x4*)(l1 + 4) = p3;
    float s0 = bf2f(h0), s1 = bf2f(h1), s2 = bf2f(h2), s3 = bf2f(h3);
    float s4 = bf2f(h4), s5 = bf2f(h5), s6 = bf2f(h6), s7 = bf2f(h7);
    float w0 = bf2f(g0), w1 = bf2f(g1), w2 = bf2f(g2), w3 = bf2f(g3);
    float w4 = bf2f(g4), w5 = bf2f(g5), w6 = bf2f(g6), w7 = bf2f(g7);
    float sx = ((s0 * s0 + s1 * s1) + (s2 * s2 + s3 * s3)) +
               ((s4 * s4 + s5 * s5) + (s6 * s6 + s7 * s7)) +
               ((w0 * w0 + w1 * w1) + (w2 * w2 + w3 * w3)) +
               ((w4 * w4 + w5 * w5) + (w6 * w6 + w7 * w7));
    sx += __shfl_xor(sx, 16, 64);  // reduce over q (d-chunks)
    sx += __shfl_xor(sx, 32, 64);
    if (L < 16) xn[mt * 16 + L] = sx;
  }
  __syncthreads();  // xs/xn/en_s/skey ready

  // all 4 m-tiles' A-frags into registers (conflict-free ds_read_b128)
  short8 a[MT][2];
#pragma unroll
  for (int m = 0; m < MT; ++m) {
    a[m][0] = *(const short8*)(xs + ((m * 2 + 0) * 64 + L) * 8);
    a[m][1] = *(const short8*)(xs + ((m * 2 + 1) * 64 + L) * 8);
  }

  unsigned bestk[MT][4];
#pragma unroll
  for (int m = 0; m < MT; ++m)
#pragma unroll
    for (int r = 0; r < 4; ++r) bestk[m][r] = 0xFFFFFFFFu;

  // ---- K-loop: explicit 1-deep register prefetch of B-frags + env ----------
  const unsigned short* bp = cb_bf + (size_t)(cbase + c16) * DDIM + q * 8;
  short8 nb0 = *(const short8*)(bp);
  short8 nb1 = *(const short8*)(bp + 32);
  float nenv = en_s[cbase + c16];
#pragma unroll
  for (int nt = 0; nt < NT; ++nt) {
    short8 b0 = nb0, b1 = nb1;
    float env = nenv;
    if (nt < NT - 1) {
      nb0 = *(const short8*)(bp + (nt + 1) * 16 * DDIM);
      nb1 = *(const short8*)(bp + (nt + 1) * 16 * DDIM + 32);
      nenv = en_s[cbase + (nt + 1) * 16 + c16];
    }
    unsigned kidx = (unsigned)(cbase + nt * 16 + c16);
#pragma unroll
    for (int m = 0; m < MT; ++m) {
      f32x4 z = {0.f, 0.f, 0.f, 0.f};
      f32x4 acc = __builtin_amdgcn_mfma_f32_16x16x32_bf16(a[m][0], b0, z, 0, 0, 0);
      acc = __builtin_amdgcn_mfma_f32_16x16x32_bf16(a[m][1], b1, acc, 0, 0, 0);
#pragma unroll
      for (int r = 0; r < 4; ++r) {
        // p = (1+||e||^2) - 2 x.e  in [0.8,1.2] -> bitcast monotone
        float p = fmaf(-2.f, acc[r], env);
        unsigned key = (__builtin_bit_cast(unsigned, p) & 0xFFFFFC00u) | kidx;
        bestk[m][r] = key < bestk[m][r] ? key : bestk[m][r];
      }
    }
  }

  // fold 16 code-columns (lanes differing in c16), then cross-wave combine
#pragma unroll
  for (int m = 0; m < MT; ++m)
#pragma unroll
    for (int r = 0; r < 4; ++r) {
      unsigned k = bestk[m][r];
      k = min(k, (unsigned)__shfl_xor((int)k, 1, 64));
      k = min(k, (unsigned)__shfl_xor((int)k, 2, 64));
      k = min(k, (unsigned)__shfl_xor((int)k, 4, 64));
      k = min(k, (unsigned)__shfl_xor((int)k, 8, 64));
      if (c16 == 0) atomicMin(&skey[m * 16 + q * 4 + r], k);  // LDS atomic
    }
  __syncthreads();

  // gather fp32 codebook row -> output (x + (e-x) == e exactly in fp32 here)
#pragma unroll
  for (int i = 0; i < 4; ++i) {
    int f = i * 256 + tid;  // float4 id in block tile [0,1024)
    int v = f >> 4, d4 = f & 15;
    int id = (int)(skey[v] & 1023u);
    ((float4*)out)[(size_t)vblk * 16 + f] = ((const float4*)cb)[(size_t)id * 16 + d4];
  }

  // loss partial: dist^2 = (p_trunc - 1) + ||x_bf||^2 ; per-block STORE
  if (wid == 0) {
    unsigned k = skey[L];
    float pt = __builtin_bit_cast(float, k & 0xFFFFFC00u);
    float pl = (pt - 1.0f) + xn[L];
#pragma unroll
    for (int off = 32; off >= 1; off >>= 1) pl += __shfl_down(pl, off, 64);
    if (L == 0) partial[blockIdx.x] = pl;
  }
}

// ---- kernel 3: reduce 1024 partials -> loss --------------------------------
__global__ __launch_bounds__(256) void vq_loss(const float* __restrict__ partial,
                                               float* __restrict__ out) {
  int tid = threadIdx.x;
  float s = 0.f;
#pragma unroll
  for (int i = 0; i < 4; ++i) s += partial[tid + 256 * i];
#pragma unroll
  for (int off = 32; off >= 1; off >>= 1) s += __shfl_down(s, off, 64);
  __shared__ float wsum[4];
  if ((tid & 63) == 0) wsum[tid >> 6] = s;
  __syncthreads();
  if (tid == 0)
    out[NELEM] = ((wsum[0] + wsum[1]) + (wsum[2] + wsum[3])) *
                 (1.25f / (float)NELEM);  // codebook + 0.25*commitment
}

extern "C" void kernel_launch(void* const* d_in, const int* in_sizes, int n_in,
                              void* d_out, int out_size, void* d_ws,
                              size_t ws_size, hipStream_t stream) {
  const float* x = (const float*)d_in[0];   // [65536, 64]
  const float* cb = (const float*)d_in[1];  // [1024, 64]
  float* out = (float*)d_out;               // [NELEM] quantized + [1] loss
  char* ws = (char*)d_ws;
  unsigned short* cb_bf = (unsigned short*)ws;  // 128 KB
  float* en1 = (float*)(ws + 131072);           // 4 KB
  float* partial = (float*)(ws + 135168);       // 4 KB (1024 floats)

  vq_prep<<<64, 256, 0, stream>>>(cb, cb_bf, en1);
  vq_main<<<NVEC / VPB, 256, 0, stream>>>(x, cb, cb_bf, en1, out, partial);
  vq_loss<<<1, 256, 0, stream>>>(partial, out);
}

// Round 8
// 97.914 us; speedup vs baseline: 1.8838x; 1.7095x over previous
//
#include <hip/hip_runtime.h>

typedef __attribute__((ext_vector_type(8))) short short8;     // 8 bf16 = 4 VGPRs
typedef __attribute__((ext_vector_type(4))) float f32x4;
typedef __attribute__((ext_vector_type(4))) unsigned short u16x4;

#define NVEC 65536
#define DDIM 64
#define KCODES 1024
#define NELEM 4194304   // NVEC * DDIM
#define VPB 256         // vectors per block; grid 256 = 1 block/CU
#define NSTAGE 4        // 256 codes per LDS stage (32 KB)

// fp32 -> bf16 round-to-nearest-even (no NaN/inf in this problem)
static __device__ inline unsigned short f2bf(float f) {
  unsigned u = __builtin_bit_cast(unsigned, f);
  return (unsigned short)((u + 0x7FFFu + ((u >> 16) & 1u)) >> 16);
}
static __device__ inline float bf2f(unsigned short b) {
  return __builtin_bit_cast(float, (unsigned)b << 16);
}

// ---- kernel 1a: en1[k] = 1 + ||e_bf||^2 ------------------------------------
__global__ __launch_bounds__(256) void vq_prep_en(const float* __restrict__ cb,
                                                  float* __restrict__ en1) {
  int t = blockIdx.x * 256 + threadIdx.x;  // float4 id, 16384 total
  float4 v = ((const float4*)cb)[t];
  float e0 = bf2f(f2bf(v.x)), e1 = bf2f(f2bf(v.y));
  float e2 = bf2f(f2bf(v.z)), e3 = bf2f(f2bf(v.w));
  float s = (e0 * e0 + e1 * e1) + (e2 * e2 + e3 * e3);
  s += __shfl_xor(s, 1, 64);
  s += __shfl_xor(s, 2, 64);
  s += __shfl_xor(s, 4, 64);
  s += __shfl_xor(s, 8, 64);
  if ((t & 15) == 0) en1[t >> 4] = 1.0f + s;  // +1 keeps scores in [0.8,1.2]>0
}

// ---- kernel 1b: cb -> bf16 frag-line swizzled ------------------------------
// chunk f in [0,8192): lane=f&63, h=(f>>6)&1, gnt=f>>7 ;
// code = gnt*16 + (lane&15), d = h*32 + ((lane>>4)&3)*8  (B-frag layout)
__global__ __launch_bounds__(256) void vq_prep_swz(const float* __restrict__ cb,
                                                   unsigned short* __restrict__ swz) {
  int f = blockIdx.x * 256 + threadIdx.x;  // 32 blocks
  int lane = f & 63, h = (f >> 6) & 1, gnt = f >> 7;
  int code = gnt * 16 + (lane & 15);
  int d = h * 32 + ((lane >> 4) & 3) * 8;
  const float4* p = (const float4*)(cb + (size_t)code * DDIM + d);
  float4 u0 = p[0], u1 = p[1];
  u16x4 p0 = {f2bf(u0.x), f2bf(u0.y), f2bf(u0.z), f2bf(u0.w)};
  u16x4 p1 = {f2bf(u1.x), f2bf(u1.y), f2bf(u1.z), f2bf(u1.w)};
  *(u16x4*)(swz + (size_t)f * 8) = p0;
  *(u16x4*)(swz + (size_t)f * 8 + 4) = p1;
}

// ---- kernel 2: LDS-codebook MFMA argmin + gather + output + loss partial ---
// 1024 threads = 16 waves; block = 256 vectors x all 1024 codes.
// Wave w: m-group (w&3)*64 (4 m-tiles, A-frags direct from x, 32 VGPR) x
// code chunk (w>>2)*64 within each of 4 staged 256-code LDS tiles (32 KB,
// frag-line layout -> conflict-free ds_read_b128 at lane*16). No global
// loads in the K-loop => L2-thrash latency gone. unroll 2 only, no manual
// prefetch (R6/R7: full unroll + prefetch -> load hoisting -> spill ->
// 160-238 MB scratch traffic). Argmin: packed u32 key (score>0 -> bitcast
// monotone)|10-bit idx, v_min_u32; cross-wave LDS atomicMin.
__global__ __launch_bounds__(1024) void vq_main(
    const float* __restrict__ x, const float* __restrict__ cb,
    const unsigned short* __restrict__ swz, const float* __restrict__ en1,
    float* __restrict__ out, float* __restrict__ partial) {
  __shared__ alignas(16) short es[2048 * 8];  // 32 KB: one 256-code stage
  __shared__ float en_s[KCODES];              // 4 KB
  __shared__ unsigned skey[VPB];              // 1 KB
  __shared__ float xn[VPB];                   // 1 KB
  __shared__ float wsum[4];

  const int tid = threadIdx.x;
  const int wid = tid >> 6;
  const int L = tid & 63;
  const int c16 = L & 15;
  const int q = L >> 4;
  const int vblk = blockIdx.x * VPB;
  const int mgrp = wid & 3;    // which 64-vector group
  const int cq = wid >> 2;     // which 64-code chunk inside each stage

  if (tid < KCODES) en_s[tid] = en1[tid];
  if (tid < VPB) skey[tid] = 0xFFFFFFFFu;

  // ---- A-frags direct from global; per-vector ||x_bf||^2 -------------------
  short8 a[4][2];
#pragma unroll
  for (int mt = 0; mt < 4; ++mt) {
    const float* xv = x + (size_t)(vblk + mgrp * 64 + mt * 16 + c16) * DDIM + q * 8;
    float4 u0 = *(const float4*)(xv);
    float4 u1 = *(const float4*)(xv + 4);
    float4 u2 = *(const float4*)(xv + 32);
    float4 u3 = *(const float4*)(xv + 36);
    unsigned short h0 = f2bf(u0.x), h1 = f2bf(u0.y), h2 = f2bf(u0.z), h3 = f2bf(u0.w);
    unsigned short h4 = f2bf(u1.x), h5 = f2bf(u1.y), h6 = f2bf(u1.z), h7 = f2bf(u1.w);
    unsigned short g0 = f2bf(u2.x), g1 = f2bf(u2.y), g2 = f2bf(u2.z), g3 = f2bf(u2.w);
    unsigned short g4 = f2bf(u3.x), g5 = f2bf(u3.y), g6 = f2bf(u3.z), g7 = f2bf(u3.w);
    short8 A0 = {(short)h0, (short)h1, (short)h2, (short)h3,
                 (short)h4, (short)h5, (short)h6, (short)h7};
    short8 A1 = {(short)g0, (short)g1, (short)g2, (short)g3,
                 (short)g4, (short)g5, (short)g6, (short)g7};
    a[mt][0] = A0;
    a[mt][1] = A1;
    float s0 = bf2f(h0), s1 = bf2f(h1), s2 = bf2f(h2), s3 = bf2f(h3);
    float s4 = bf2f(h4), s5 = bf2f(h5), s6 = bf2f(h6), s7 = bf2f(h7);
    float w0 = bf2f(g0), w1 = bf2f(g1), w2 = bf2f(g2), w3 = bf2f(g3);
    float w4 = bf2f(g4), w5 = bf2f(g5), w6 = bf2f(g6), w7 = bf2f(g7);
    float sx = ((s0 * s0 + s1 * s1) + (s2 * s2 + s3 * s3)) +
               ((s4 * s4 + s5 * s5) + (s6 * s6 + s7 * s7)) +
               ((w0 * w0 + w1 * w1) + (w2 * w2 + w3 * w3)) +
               ((w4 * w4 + w5 * w5) + (w6 * w6 + w7 * w7));
    sx += __shfl_xor(sx, 16, 64);  // reduce over q
    sx += __shfl_xor(sx, 32, 64);
    if (cq == 0 && L < 16) xn[mgrp * 64 + mt * 16 + L] = sx;
  }

  unsigned bestk[4][4];
#pragma unroll
  for (int m = 0; m < 4; ++m)
#pragma unroll
    for (int r = 0; r < 4; ++r) bestk[m][r] = 0xFFFFFFFFu;

  // ---- staged K-loop: 4 x (stage 256 codes -> LDS; consume) ---------------
  for (int s = 0; s < NSTAGE; ++s) {
    __syncthreads();  // prior-stage readers done (also fences preamble LDS)
    ((short8*)es)[tid] = ((const short8*)swz)[s * 2048 + tid];
    ((short8*)es)[tid + 1024] = ((const short8*)swz)[s * 2048 + 1024 + tid];
    __syncthreads();

#pragma unroll 2
    for (int nt = 0; nt < 4; ++nt) {
      short8 b0 = ((const short8*)es)[((cq * 4 + nt) * 2 + 0) * 64 + L];
      short8 b1 = ((const short8*)es)[((cq * 4 + nt) * 2 + 1) * 64 + L];
      int code0 = s * 256 + cq * 64 + nt * 16;  // global code of column c16==0
      float env = en_s[code0 + c16];
      unsigned kidx = (unsigned)(code0 + c16);
#pragma unroll
      for (int m = 0; m < 4; ++m) {
        f32x4 z = {0.f, 0.f, 0.f, 0.f};
        f32x4 acc = __builtin_amdgcn_mfma_f32_16x16x32_bf16(a[m][0], b0, z, 0, 0, 0);
        acc = __builtin_amdgcn_mfma_f32_16x16x32_bf16(a[m][1], b1, acc, 0, 0, 0);
#pragma unroll
        for (int r = 0; r < 4; ++r) {
          // p = (1+||e||^2) - 2 x.e  in [0.8,1.2] -> bitcast monotone
          float p = fmaf(-2.f, acc[r], env);
          unsigned key = (__builtin_bit_cast(unsigned, p) & 0xFFFFFC00u) | kidx;
          bestk[m][r] = key < bestk[m][r] ? key : bestk[m][r];
        }
      }
    }
  }

  // fold 16 code-columns (lanes differing in c16), then cross-wave combine
#pragma unroll
  for (int m = 0; m < 4; ++m)
#pragma unroll
    for (int r = 0; r < 4; ++r) {
      unsigned k = bestk[m][r];
      k = min(k, (unsigned)__shfl_xor((int)k, 1, 64));
      k = min(k, (unsigned)__shfl_xor((int)k, 2, 64));
      k = min(k, (unsigned)__shfl_xor((int)k, 4, 64));
      k = min(k, (unsigned)__shfl_xor((int)k, 8, 64));
      if (c16 == 0) atomicMin(&skey[mgrp * 64 + m * 16 + q * 4 + r], k);  // LDS
    }
  __syncthreads();

  // gather fp32 codebook row -> output (x + (e-x) == e exactly in fp32 here)
#pragma unroll
  for (int i = 0; i < 4; ++i) {
    int f = i * 1024 + tid;  // float4 id in block tile [0,4096)
    int v = f >> 4, d4 = f & 15;
    int id = (int)(skey[v] & 1023u);
    ((float4*)out)[(size_t)vblk * 16 + f] = ((const float4*)cb)[(size_t)id * 16 + d4];
  }

  // loss partial: dist^2 = (p_trunc - 1) + ||x_bf||^2 ; per-block STORE
  if (tid < VPB) {
    unsigned k = skey[tid];
    float pt = __builtin_bit_cast(float, k & 0xFFFFFC00u);
    float pl = (pt - 1.0f) + xn[tid];
#pragma unroll
    for (int off = 32; off >= 1; off >>= 1) pl += __shfl_down(pl, off, 64);
    if (L == 0) wsum[wid] = pl;
  }
  __syncthreads();
  if (tid == 0)
    partial[blockIdx.x] = (wsum[0] + wsum[1]) + (wsum[2] + wsum[3]);
}

// ---- kernel 3: reduce 256 partials -> loss ---------------------------------
__global__ __launch_bounds__(256) void vq_loss(const float* __restrict__ partial,
                                               float* __restrict__ out) {
  int tid = threadIdx.x;
  float s = partial[tid];
#pragma unroll
  for (int off = 32; off >= 1; off >>= 1) s += __shfl_down(s, off, 64);
  __shared__ float wsum2[4];
  if ((tid & 63) == 0) wsum2[tid >> 6] = s;
  __syncthreads();
  if (tid == 0)
    out[NELEM] = ((wsum2[0] + wsum2[1]) + (wsum2[2] + wsum2[3])) *
                 (1.25f / (float)NELEM);  // codebook + 0.25*commitment
}

extern "C" void kernel_launch(void* const* d_in, const int* in_sizes, int n_in,
                              void* d_out, int out_size, void* d_ws,
                              size_t ws_size, hipStream_t stream) {
  const float* x = (const float*)d_in[0];   // [65536, 64]
  const float* cb = (const float*)d_in[1];  // [1024, 64]
  float* out = (float*)d_out;               // [NELEM] quantized + [1] loss
  char* ws = (char*)d_ws;
  unsigned short* swz = (unsigned short*)ws;    // 128 KB frag-swizzled bf16 cb
  float* en1 = (float*)(ws + 131072);           // 4 KB
  float* partial = (float*)(ws + 135168);       // 1 KB (256 floats)

  vq_prep_en<<<64, 256, 0, stream>>>(cb, en1);
  vq_prep_swz<<<32, 256, 0, stream>>>(cb, swz);
  vq_main<<<NVEC / VPB, 1024, 0, stream>>>(x, cb, swz, en1, out, partial);
  vq_loss<<<1, 256, 0, stream>>>(partial, out);
}